// Round 19
// baseline (154.204 us; speedup 1.0000x reference)
//
#include <hip/hip_runtime.h>
#include <math.h>

typedef unsigned short us;
typedef __attribute__((ext_vector_type(8))) short bf16x8;
typedef __attribute__((ext_vector_type(4))) float f32x4;

// Problem dims
constexpr int B_  = 4;
constexpr int T_  = 16;
constexpr int CIN = 32;
constexpr int HID = 64;
constexpr int HH  = 64;
constexpr int WW  = 64;
constexpr int HW  = HH * WW;

// ---------------- config ----------------
constexpr int CSL = 40;                       // channel slots per pixel (80B)
constexpr int KCH = 32;
constexpr int ASLAB_HW = 3 * 36 * 16 * 8;     // 13824 hw per (chunk,hg) slab
constexpr int ATOTAL   = 12 * ASLAB_HW;
constexpr int ROW_HW   = 66 * CSL;            // 2640 hw per padded row
constexpr int PIMG_HW  = 66 * ROW_HW;         // padded image (1-px ring)
// step tile: out 4x16; halo 6x18
constexpr int T6_HW  = 6 * 18 * CSL;          // 4320 hw (8640 B)
constexpr int T6_GR  = T6_HW / 8;             // 540 granules

// ws layout (halfword offsets)
constexpr size_t XT_OFF   = (size_t)ATOTAL;
constexpr size_t XT_HW    = (size_t)64 * PIMG_HW;
constexpr size_t HT_OFF   = XT_OFF + XT_HW;
constexpr size_t HTBUF_HW = (size_t)8 * PIMG_HW;   // [b4][chunk2] images
constexpr size_t WS_NEED_BYTES = (HT_OFF + 2 * HTBUF_HW) * 2;

// ring-only hzero: per image, zero row0, row65, and cols {0,65} of rows 1..64
constexpr int RING_GR_IMG = 330 + 330 + 64 * 10;   // 1300 16B granules per image
constexpr int RING_GR_TOT = 16 * RING_GR_IMG;      // 16 images (2 bufs x 8)

// fused prepass block ranges
constexpr int PB_XFILL = 66 * 64;
constexpr int PB_WCONV = (ATOTAL + 255) / 256;
constexpr int PB_HZERO = (RING_GR_TOT + 255) / 256;
constexpr int PB_TOTAL = PB_XFILL + PB_WCONV + PB_HZERO;

#define GLOAD_LDS16(gsrc, ldst) \
  __builtin_amdgcn_global_load_lds((const __attribute__((address_space(1))) void*)(gsrc), \
                                   (__attribute__((address_space(3))) void*)(ldst), 16, 0, 0)
#define MFMA_B(d, A, Bv) d = __builtin_amdgcn_mfma_f32_16x16x32_bf16(A, Bv, d, 0, 0, 0)

__device__ inline us f2bf(float f) {
    union { float f; unsigned u; } v; v.f = f;
    return (us)((v.u + 0x7FFFu + ((v.u >> 16) & 1u)) >> 16);
}
__device__ inline float bf2f(us h) {
    union { unsigned u; float f; } v; v.u = (unsigned)h << 16; return v.f;
}

// ---- fused prepass: xfill | wconv | ring-hzero (unchanged from r18) ----
__global__ void prep(const float* __restrict__ x,
                     const float* __restrict__ Wi, const float* __restrict__ Wh,
                     us* __restrict__ A2, us* __restrict__ xT, us* __restrict__ hT) {
    __shared__ float lds[64 * 41];
    const int bid = blockIdx.x;

    if (bid < PB_XFILL) {
        const int riT = bid % 66;
        const int bt  = bid / 66;
        us* dst = xT + (size_t)bt * PIMG_HW + (size_t)riT * ROW_HW;
        const bool interior = (riT >= 1 && riT <= 64);
        if (interior) {
            const float* src = x + (size_t)bt * 32 * HW + (riT - 1) * WW;
            const int p = threadIdx.x & 63;
            #pragma unroll
            for (int j = 0; j < 8; ++j) {
                int c = j * 4 + (threadIdx.x >> 6);
                lds[p * 41 + c] = src[c * HW + p];
            }
        }
        __syncthreads();
        for (int g = threadIdx.x; g < ROW_HW / 8; g += 256) {
            bf16x8 vv;
            #pragma unroll
            for (int k = 0; k < 8; ++k) {
                int off = g * 8 + k;
                int px = off / CSL, slot = off - px * CSL;
                float v = 0.f;
                if (interior && slot < 32 && px >= 1 && px <= 64)
                    v = lds[(px - 1) * 41 + slot];
                vv[k] = (short)f2bf(v);
            }
            *(bf16x8*)(dst + g * 8) = vv;
        }
    } else if (bid < PB_XFILL + PB_WCONV) {
        int idx = (bid - PB_XFILL) * 256 + threadIdx.x;
        if (idx >= ATOTAL) return;
        int ic  = idx & 31;
        int r1  = idx >> 5;
        int tap = r1 % 9;
        int r2  = r1 / 9;
        int m   = r2 & 15;
        int r3  = r2 >> 4;
        int gt  = r3 % 3;
        int r4  = r3 / 3;
        int hg  = r4 & 3;
        int ch  = r4 >> 2;
        int o   = gt * 64 + hg * 16 + m;
        float w = (ch == 0) ? Wi[(o * CIN + ic) * 9 + tap]
                            : Wh[(o * HID + (ch - 1) * 32 + ic) * 9 + tap];
        size_t dst = (size_t)(ch * 4 + hg) * ASLAB_HW
                   + ((size_t)(gt * 36 + tap * 4 + (ic >> 3)) * 16 + m) * 8 + (ic & 7);
        A2[dst] = f2bf(w);
    } else {
        int i = (bid - PB_XFILL - PB_WCONV) * 256 + threadIdx.x;
        if (i >= RING_GR_TOT) return;
        int img = i / RING_GR_IMG;
        int g   = i - img * RING_GR_IMG;
        size_t off;
        if (g < 330)            off = (size_t)g * 8;
        else if (g < 660)       off = (size_t)65 * ROW_HW + (size_t)(g - 330) * 8;
        else {
            int k = g - 660;
            int r = 1 + k / 10, c = k % 10;
            off = (size_t)r * ROW_HW + ((c < 5) ? (size_t)c * 8
                                                : (size_t)65 * CSL + (size_t)(c - 5) * 8);
        }
        bf16x8 z = {};
        *(bf16x8*)(hT + (size_t)img * PIMG_HW + off) = z;
    }
}

// ---- step kernel: tile 4x16 x 64ch, 4 waves (one per hg) ----
// Two-barrier schedule: h-DMA overlapped with x-chunk compute.
// grid (64 tiles, 1, 4 b), 256 thr, 1 block/CU.
__global__ __launch_bounds__(256, 1) void convgru_step(
    const us* __restrict__ xT, const us* __restrict__ A2,
    const us* __restrict__ hTrd, us* __restrict__ hTwr,
    float* __restrict__ out, int t)
{
    __shared__ __align__(16) us t0s[T6_HW];  // x tile
    __shared__ __align__(16) us t1s[T6_HW];  // h ch 0-31
    __shared__ __align__(16) us t2s[T6_HW];  // h ch 32-63

    const int tid  = threadIdx.x;
    const int lane = tid & 63, hg = tid >> 6;   // wave = hg
    const int px   = lane & 15, kl = lane >> 4;
    const int tile = blockIdx.x, ty = tile >> 2, tx = tile & 3, b = blockIdx.z;
    const int gy0 = ty * 4, gx0 = tx * 16;
    const int rowbase = gy0 * 66 + gx0;         // halo origin in padded image

    f32x4 aR[2][2], aZ[2][2], aNX[2][2], aNH[2][2];
    #pragma unroll
    for (int u = 0; u < 2; ++u)
        #pragma unroll
        for (int g = 0; g < 2; ++g) {
            aR[u][g] = f32x4{0.f,0.f,0.f,0.f}; aZ[u][g] = f32x4{0.f,0.f,0.f,0.f};
            aNX[u][g] = f32x4{0.f,0.f,0.f,0.f}; aNH[u][g] = f32x4{0.f,0.f,0.f,0.f};
        }
    bf16x8 a[27];

    auto stage_tin = [&](const us* src, us* dst) {
        #pragma unroll
        for (int j = 0; j < 3; ++j) {
            int G = tid + j * 256;
            if (G < T6_GR) {
                int r = G / 90, w = G - 90 * r;   // 90 granules per halo row
                GLOAD_LDS16(src + (size_t)(rowbase + r * 66) * CSL + w * 8, dst + G * 8);
            }
        }
    };
    auto regA = [&](int ch) {
        const us* s = A2 + (size_t)(ch * 4 + hg) * ASLAB_HW + lane * 8;
        #pragma unroll
        for (int i = 0; i < 27; ++i)
            a[i] = *(const bf16x8*)(s + (size_t)((i / 9) * 36 + (i % 9) * 4) * 128);
    };

    const int rbase = px * CSL + kl * 8;

    auto compute = [&](const us* tb, bool isX, const us* nextA) {
        #pragma unroll
        for (int dx = 0; dx < 3; ++dx) {
            bf16x8 P[6];
            #pragma unroll
            for (int r = 0; r < 6; ++r)
                P[r] = *(const bf16x8*)(tb + (r * 18 + dx) * CSL + rbase);
            #pragma unroll
            for (int dy = 0; dy < 3; ++dy) {
                const int tap = dy * 3 + dx;
                bf16x8 ar = a[tap], az = a[9 + tap], an = a[18 + tap];
                if (nextA) {   // pipelined reload of this tap's fragments
                    a[tap]      = *(const bf16x8*)(nextA + (size_t)(0 * 36 + tap * 4) * 128);
                    a[9 + tap]  = *(const bf16x8*)(nextA + (size_t)(1 * 36 + tap * 4) * 128);
                    a[18 + tap] = *(const bf16x8*)(nextA + (size_t)(2 * 36 + tap * 4) * 128);
                }
                #pragma unroll
                for (int u = 0; u < 2; ++u) {
                    bf16x8 b0 = P[2 * u + dy], b1 = P[2 * u + dy + 1];
                    MFMA_B(aR[u][0], ar, b0); MFMA_B(aR[u][1], ar, b1);
                    MFMA_B(aZ[u][0], az, b0); MFMA_B(aZ[u][1], az, b1);
                    if (isX) { MFMA_B(aNX[u][0], an, b0); MFMA_B(aNX[u][1], an, b1); }
                    else     { MFMA_B(aNH[u][0], an, b0); MFMA_B(aNH[u][1], an, b1); }
                }
            }
        }
    };

    const us* A1p = (t > 0) ? A2 + (size_t)(1 * 4 + hg) * ASLAB_HW + lane * 8 : nullptr;
    const us* A2p = (t > 0) ? A2 + (size_t)(2 * 4 + hg) * ASLAB_HW + lane * 8 : nullptr;

    // ---- two-barrier schedule: x first, h-DMA under x-compute ----
    stage_tin(xT + (size_t)(b * T_ + t) * PIMG_HW, t0s);
    regA(0);
    __syncthreads();                          // x tile + A(0) ready (h not yet issued)

    if (t > 0) {
        stage_tin(hTrd + (size_t)(b * 2 + 0) * PIMG_HW, t1s);   // DMA in flight...
        stage_tin(hTrd + (size_t)(b * 2 + 1) * PIMG_HW, t2s);
    }
    compute(t0s, true, A1p);                  // ...hidden under x-chunk MFMA
    if (t > 0) {
        __syncthreads();                      // h tiles ready
        compute(t1s, false, A2p);
        compute(t2s, false, nullptr);
    }

    // ---- epilogue ----
    float* outp = out + ((size_t)(b * T_ + t)) * HID * HW;
    const int c0   = hg * 16 + kl * 4;
    const int slot = c0 & 31;
    const us* hbuf = (hg < 2) ? t1s : t2s;
    #pragma unroll
    for (int u = 0; u < 2; ++u) {
        #pragma unroll
        for (int g = 0; g < 2; ++g) {
            int orow = 2 * u + g;                 // 0..3
            int gy = gy0 + orow, gx = gx0 + px;
            float hvf[4] = {0.f, 0.f, 0.f, 0.f};
            if (t > 0) {
                const us* hp = hbuf + (size_t)((orow + 1) * 18 + (px + 1)) * CSL + slot;
                #pragma unroll
                for (int q = 0; q < 4; ++q) hvf[q] = bf2f(hp[q]);
            }
            us hv[4];
            #pragma unroll
            for (int q = 0; q < 4; ++q) {
                float sr = __builtin_amdgcn_rcpf(1.f + __expf(-aR[u][g][q]));
                float sz = __builtin_amdgcn_rcpf(1.f + __expf(-aZ[u][g][q]));
                float ag = aNX[u][g][q] + sr * aNH[u][g][q];
                float nn = 2.f * __builtin_amdgcn_rcpf(1.f + __expf(-2.f * ag)) - 1.f;
                float hn = nn + sz * (hvf[q] - nn);
                outp[(size_t)(c0 + q) * HW + gy * WW + gx] = hn;
                hv[q] = f2bf(hn);
            }
            us* hd = hTwr + (size_t)(b * 2 + (c0 >> 5)) * PIMG_HW
                   + (size_t)((gy + 1) * 66 + (gx + 1)) * CSL + slot;
            *(uint2*)hd = *(const uint2*)hv;
        }
    }
}

// ================= round-4 fallback (tiny ws) =================
constexpr int F_AROWB = 640;
constexpr int R4_ASLAB = 48 * 9 * KCH;
constexpr int R4_AVEC  = R4_ASLAB / 8;
constexpr int R4_ATOT  = 12 * R4_ASLAB;
constexpr int FPR = 10, FPC = 18;
__global__ void wconv_r4(const float* __restrict__ Wi, const float* __restrict__ Wh,
                         us* __restrict__ A2) {
    int idx = blockIdx.x * 256 + threadIdx.x;
    if (idx >= R4_ATOT) return;
    int ic = idx & 31; int r1 = idx >> 5;
    int tap = r1 % 9; int r2 = r1 / 9;
    int m = r2 & 15; int r3 = r2 >> 4;
    int gt = r3 % 3; int r4 = r3 / 3;
    int hg = r4 & 3; int ch = r4 >> 2;
    int o = gt * 64 + hg * 16 + m;
    float w = (ch == 0) ? Wi[(o * CIN + ic) * 9 + tap]
                        : Wh[(o * HID + (ch - 1) * 32 + ic) * 9 + tap];
    A2[idx] = f2bf(w);
}
__global__ __launch_bounds__(256, 2) void convgru_r4(
    const float* __restrict__ x, const us* __restrict__ A2,
    const float* hall, float* out, int t)
{
    __shared__ __align__(16) us tin[FPR * FPC * 40];
    __shared__ __align__(16) us Alr[48 * (F_AROWB / 2)];
    const int tid = threadIdx.x;
    const int lane = tid & 63, wave = tid >> 6;
    const int px = lane & 15, kl = lane >> 4;
    const int ty = blockIdx.x >> 2, tx = blockIdx.x & 3;
    const int hg = blockIdx.y, b = blockIdx.z;
    const int gy0 = ty * 8, gx0 = tx * 16;
    const int nch = (t > 0) ? 3 : 1;
    const float* hb = (t > 0) ? (hall + ((size_t)(b * T_ + t - 1)) * HID * HW) : nullptr;
    const float* xb = x + ((size_t)(b * T_ + t)) * CIN * HW;
    f32x4 accR[2] = {}, accZ[2] = {}, accNX[2] = {}, accNH[2] = {};
    float ireg[23]; bf16x8 areg[7];
    auto load_in = [&](int ch) {
        const float* src = (ch == 0) ? xb : (hb + (size_t)(ch - 1) * 32 * HW);
        #pragma unroll
        for (int j = 0; j < 23; ++j) {
            int e = tid + j * 256; float v = 0.f;
            if (e < FPR * FPC * 32) {
                int ic = e / (FPR * FPC); int rem = e - ic * (FPR * FPC);
                int r = rem / FPC, c = rem - r * FPC;
                int gy = gy0 + r - 1, gx = gx0 + c - 1;
                if ((unsigned)gy < (unsigned)HH && (unsigned)gx < (unsigned)WW)
                    v = src[ic * HW + gy * WW + gx];
            }
            ireg[j] = v;
        }
    };
    auto load_Ar = [&](int ch) {
        const us* s = A2 + (size_t)(ch * 4 + hg) * R4_ASLAB;
        #pragma unroll
        for (int j = 0; j < 7; ++j) { int v = tid + j * 256; if (v < R4_AVEC) areg[j] = *(const bf16x8*)(s + v * 8); }
    };
    auto write_in = [&]() {
        #pragma unroll
        for (int j = 0; j < 23; ++j) {
            int e = tid + j * 256;
            if (e < FPR * FPC * 32) {
                int ic = e / (FPR * FPC); int rem = e - ic * (FPR * FPC);
                int r = rem / FPC, c = rem - r * FPC;
                tin[(r * FPC + c) * 40 + ic] = f2bf(ireg[j]);
            }
        }
    };
    auto write_Ar = [&]() {
        #pragma unroll
        for (int j = 0; j < 7; ++j) {
            int v = tid + j * 256;
            if (v < R4_AVEC) {
                int row = v / 36; int kb = (v - row * 36) * 16;
                char* dst = (char*)Alr + row * F_AROWB + (kb ^ ((row & 7) << 4));
                *(bf16x8*)dst = areg[j];
            }
        }
    };
    const int rb0 = ((wave * 2 + 0) * FPC + px) * 40 + kl * 8;
    const int rb1 = rb0 + FPC * 40;
    const int swA = (px & 7) << 4;
    auto compute = [&](bool isX) {
        #pragma unroll
        for (int tap = 0; tap < 9; ++tap) {
            const int dy = tap / 3, dx = tap - 3 * dy;
            const int toff = (dy * FPC + dx) * 40;
            bf16x8 b0 = *(const bf16x8*)(tin + rb0 + toff);
            bf16x8 b1 = *(const bf16x8*)(tin + rb1 + toff);
            const char* ab = (const char*)Alr + px * F_AROWB + ((tap * 64 + kl * 16) ^ swA);
            bf16x8 ar = *(const bf16x8*)(ab);
            bf16x8 az = *(const bf16x8*)(ab + 16 * F_AROWB);
            bf16x8 an = *(const bf16x8*)(ab + 32 * F_AROWB);
            MFMA_B(accR[0], ar, b0); MFMA_B(accR[1], ar, b1);
            MFMA_B(accZ[0], az, b0); MFMA_B(accZ[1], az, b1);
            if (isX) { MFMA_B(accNX[0], an, b0); MFMA_B(accNX[1], an, b1); }
            else     { MFMA_B(accNH[0], an, b0); MFMA_B(accNH[1], an, b1); }
        }
    };
    load_in(0); load_Ar(0); write_in(); write_Ar();
    __syncthreads();
    for (int ch = 0; ch < nch; ++ch) {
        if (ch + 1 < nch) { load_in(ch + 1); load_Ar(ch + 1); }
        compute(ch == 0);
        __syncthreads();
        if (ch + 1 < nch) { write_in(); write_Ar(); __syncthreads(); }
    }
    float* outp = out + ((size_t)(b * T_ + t)) * HID * HW;
    #pragma unroll
    for (int g = 0; g < 2; ++g) {
        int gy = gy0 + wave * 2 + g; int gx = gx0 + px;
        #pragma unroll
        for (int q = 0; q < 4; ++q) {
            int c = hg * 16 + kl * 4 + q;
            float sr = 1.f / (1.f + expf(-accR[g][q]));
            float sz = 1.f / (1.f + expf(-accZ[g][q]));
            float nn = tanhf(accNX[g][q] + sr * accNH[g][q]);
            float hv = hb ? hb[(size_t)c * HW + gy * WW + gx] : 0.f;
            outp[(size_t)c * HW + gy * WW + gx] = (1.f - sz) * nn + sz * hv;
        }
    }
}

extern "C" void kernel_launch(void* const* d_in, const int* in_sizes, int n_in,
                              void* d_out, int out_size, void* d_ws, size_t ws_size,
                              hipStream_t stream) {
    const float* x  = (const float*)d_in[0];
    const float* Wi = (const float*)d_in[1];
    const float* Wh = (const float*)d_in[2];
    float* out = (float*)d_out;

    if (ws_size >= WS_NEED_BYTES) {
        us* A2  = (us*)d_ws;
        us* xT  = A2 + XT_OFF;
        us* hT0 = A2 + HT_OFF;
        us* hT1 = hT0 + HTBUF_HW;

        prep<<<PB_TOTAL, 256, 0, stream>>>(x, Wi, Wh, A2, xT, hT0);
        for (int t = 0; t < T_; ++t) {
            us* rd = (t & 1) ? hT1 : hT0;
            us* wr = (t & 1) ? hT0 : hT1;
            convgru_step<<<dim3(64, 1, 4), 256, 0, stream>>>(xT, A2, rd, wr, out, t);
        }
    } else {
        us* A2 = (us*)d_ws;
        wconv_r4<<<(R4_ATOT + 255) / 256, 256, 0, stream>>>(Wi, Wh, A2);
        for (int t = 0; t < T_; ++t)
            convgru_r4<<<dim3(32, 4, 4), 256, 0, stream>>>(x, A2, out, out, t);
    }
}

// Round 20
// 151.610 us; speedup vs baseline: 1.0171x; 1.0171x over previous
//
#include <hip/hip_runtime.h>
#include <math.h>

typedef unsigned short us;
typedef __attribute__((ext_vector_type(8))) short bf16x8;
typedef __attribute__((ext_vector_type(4))) float f32x4;

// Problem dims
constexpr int B_  = 4;
constexpr int T_  = 16;
constexpr int CIN = 32;
constexpr int HID = 64;
constexpr int HH  = 64;
constexpr int WW  = 64;
constexpr int HW  = HH * WW;

// ---------------- config ----------------
constexpr int CSL = 40;                       // channel slots per pixel (80B)
constexpr int KCH = 32;
constexpr int ASLAB_HW = 3 * 36 * 16 * 8;     // 13824 hw per (chunk,hg) slab
constexpr int ATOTAL   = 12 * ASLAB_HW;
constexpr int ROW_HW   = 66 * CSL;            // 2640 hw per padded row
constexpr int PIMG_HW  = 66 * ROW_HW;         // padded image (1-px ring)
// step tile: out 4x16; halo 6x18
constexpr int T6_HW  = 6 * 18 * CSL;          // 4320 hw (8640 B)
constexpr int T6_GR  = T6_HW / 8;             // 540 granules

// ws layout (halfword offsets)
constexpr size_t XT_OFF   = (size_t)ATOTAL;
constexpr size_t XT_HW    = (size_t)64 * PIMG_HW;
constexpr size_t HT_OFF   = XT_OFF + XT_HW;
constexpr size_t HTBUF_HW = (size_t)8 * PIMG_HW;   // [b4][chunk2] images
constexpr size_t WS_NEED_BYTES = (HT_OFF + 2 * HTBUF_HW) * 2;

// ring-only hzero: per image, zero row0, row65, and cols {0,65} of rows 1..64
constexpr int RING_GR_IMG = 330 + 330 + 64 * 10;   // 1300 16B granules per image
constexpr int RING_GR_TOT = 16 * RING_GR_IMG;      // 16 images (2 bufs x 8)

// fused prepass block ranges
constexpr int PB_XFILL = 66 * 64;
constexpr int PB_WCONV = (ATOTAL + 255) / 256;
constexpr int PB_HZERO = (RING_GR_TOT + 255) / 256;
constexpr int PB_TOTAL = PB_XFILL + PB_WCONV + PB_HZERO;

#define GLOAD_LDS16(gsrc, ldst) \
  __builtin_amdgcn_global_load_lds((const __attribute__((address_space(1))) void*)(gsrc), \
                                   (__attribute__((address_space(3))) void*)(ldst), 16, 0, 0)
#define MFMA_B(d, A, Bv) d = __builtin_amdgcn_mfma_f32_16x16x32_bf16(A, Bv, d, 0, 0, 0)

__device__ inline us f2bf(float f) {
    union { float f; unsigned u; } v; v.f = f;
    return (us)((v.u + 0x7FFFu + ((v.u >> 16) & 1u)) >> 16);
}
__device__ inline float bf2f(us h) {
    union { unsigned u; float f; } v; v.u = (unsigned)h << 16; return v.f;
}

// ---- fused prepass: xfill | wconv | ring-hzero ----
__global__ void prep(const float* __restrict__ x,
                     const float* __restrict__ Wi, const float* __restrict__ Wh,
                     us* __restrict__ A2, us* __restrict__ xT, us* __restrict__ hT) {
    __shared__ float lds[64 * 41];
    const int bid = blockIdx.x;

    if (bid < PB_XFILL) {
        const int riT = bid % 66;
        const int bt  = bid / 66;
        us* dst = xT + (size_t)bt * PIMG_HW + (size_t)riT * ROW_HW;
        const bool interior = (riT >= 1 && riT <= 64);
        if (interior) {
            const float* src = x + (size_t)bt * 32 * HW + (riT - 1) * WW;
            const int p = threadIdx.x & 63;
            #pragma unroll
            for (int j = 0; j < 8; ++j) {
                int c = j * 4 + (threadIdx.x >> 6);
                lds[p * 41 + c] = src[c * HW + p];
            }
        }
        __syncthreads();
        for (int g = threadIdx.x; g < ROW_HW / 8; g += 256) {
            bf16x8 vv;
            #pragma unroll
            for (int k = 0; k < 8; ++k) {
                int off = g * 8 + k;
                int px = off / CSL, slot = off - px * CSL;
                float v = 0.f;
                if (interior && slot < 32 && px >= 1 && px <= 64)
                    v = lds[(px - 1) * 41 + slot];
                vv[k] = (short)f2bf(v);
            }
            *(bf16x8*)(dst + g * 8) = vv;
        }
    } else if (bid < PB_XFILL + PB_WCONV) {
        int idx = (bid - PB_XFILL) * 256 + threadIdx.x;
        if (idx >= ATOTAL) return;
        int ic  = idx & 31;
        int r1  = idx >> 5;
        int tap = r1 % 9;
        int r2  = r1 / 9;
        int m   = r2 & 15;
        int r3  = r2 >> 4;
        int gt  = r3 % 3;
        int r4  = r3 / 3;
        int hg  = r4 & 3;
        int ch  = r4 >> 2;
        int o   = gt * 64 + hg * 16 + m;
        float w = (ch == 0) ? Wi[(o * CIN + ic) * 9 + tap]
                            : Wh[(o * HID + (ch - 1) * 32 + ic) * 9 + tap];
        size_t dst = (size_t)(ch * 4 + hg) * ASLAB_HW
                   + ((size_t)(gt * 36 + tap * 4 + (ic >> 3)) * 16 + m) * 8 + (ic & 7);
        A2[dst] = f2bf(w);
    } else {
        // ---- ring-only hzero: interiors are overwritten by step epilogues ----
        int i = (bid - PB_XFILL - PB_WCONV) * 256 + threadIdx.x;
        if (i >= RING_GR_TOT) return;
        int img = i / RING_GR_IMG;
        int g   = i - img * RING_GR_IMG;
        size_t off;
        if (g < 330)            off = (size_t)g * 8;                         // row 0
        else if (g < 660)       off = (size_t)65 * ROW_HW + (size_t)(g - 330) * 8; // row 65
        else {
            int k = g - 660;
            int r = 1 + k / 10, c = k % 10;
            off = (size_t)r * ROW_HW + ((c < 5) ? (size_t)c * 8
                                                : (size_t)65 * CSL + (size_t)(c - 5) * 8);
        }
        bf16x8 z = {};
        *(bf16x8*)(hT + (size_t)img * PIMG_HW + off) = z;
    }
}

// ---- step kernel (r15/r18): tile 4x16 x 64ch, 4 waves (one per hg) ----
// grid (64 tiles, 1, 4 b), 256 thr, 1 block/CU.
__global__ __launch_bounds__(256, 1) void convgru_step(
    const us* __restrict__ xT, const us* __restrict__ A2,
    const us* __restrict__ hTrd, us* __restrict__ hTwr,
    float* __restrict__ out, int t)
{
    __shared__ __align__(16) us t0s[T6_HW];  // x tile
    __shared__ __align__(16) us t1s[T6_HW];  // h ch 0-31
    __shared__ __align__(16) us t2s[T6_HW];  // h ch 32-63

    const int tid  = threadIdx.x;
    const int lane = tid & 63, hg = tid >> 6;   // wave = hg
    const int px   = lane & 15, kl = lane >> 4;
    const int tile = blockIdx.x, ty = tile >> 2, tx = tile & 3, b = blockIdx.z;
    const int gy0 = ty * 4, gx0 = tx * 16;
    const int rowbase = gy0 * 66 + gx0;         // halo origin in padded image

    f32x4 aR[2][2], aZ[2][2], aNX[2][2], aNH[2][2];
    #pragma unroll
    for (int u = 0; u < 2; ++u)
        #pragma unroll
        for (int g = 0; g < 2; ++g) {
            aR[u][g] = f32x4{0.f,0.f,0.f,0.f}; aZ[u][g] = f32x4{0.f,0.f,0.f,0.f};
            aNX[u][g] = f32x4{0.f,0.f,0.f,0.f}; aNH[u][g] = f32x4{0.f,0.f,0.f,0.f};
        }
    bf16x8 a[27];

    auto stage_tin = [&](const us* src, us* dst) {
        #pragma unroll
        for (int j = 0; j < 3; ++j) {
            int G = tid + j * 256;
            if (G < T6_GR) {
                int r = G / 90, w = G - 90 * r;   // 90 granules per halo row
                GLOAD_LDS16(src + (size_t)(rowbase + r * 66) * CSL + w * 8, dst + G * 8);
            }
        }
    };
    auto regA = [&](int ch) {
        const us* s = A2 + (size_t)(ch * 4 + hg) * ASLAB_HW + lane * 8;
        #pragma unroll
        for (int i = 0; i < 27; ++i)
            a[i] = *(const bf16x8*)(s + (size_t)((i / 9) * 36 + (i % 9) * 4) * 128);
    };

    const int rbase = px * CSL + kl * 8;

    auto compute = [&](const us* tb, bool isX, const us* nextA) {
        #pragma unroll
        for (int dx = 0; dx < 3; ++dx) {
            bf16x8 P[6];
            #pragma unroll
            for (int r = 0; r < 6; ++r)
                P[r] = *(const bf16x8*)(tb + (r * 18 + dx) * CSL + rbase);
            #pragma unroll
            for (int dy = 0; dy < 3; ++dy) {
                const int tap = dy * 3 + dx;
                bf16x8 ar = a[tap], az = a[9 + tap], an = a[18 + tap];
                if (nextA) {   // pipelined reload of this tap's fragments
                    a[tap]      = *(const bf16x8*)(nextA + (size_t)(0 * 36 + tap * 4) * 128);
                    a[9 + tap]  = *(const bf16x8*)(nextA + (size_t)(1 * 36 + tap * 4) * 128);
                    a[18 + tap] = *(const bf16x8*)(nextA + (size_t)(2 * 36 + tap * 4) * 128);
                }
                #pragma unroll
                for (int u = 0; u < 2; ++u) {
                    bf16x8 b0 = P[2 * u + dy], b1 = P[2 * u + dy + 1];
                    MFMA_B(aR[u][0], ar, b0); MFMA_B(aR[u][1], ar, b1);
                    MFMA_B(aZ[u][0], az, b0); MFMA_B(aZ[u][1], az, b1);
                    if (isX) { MFMA_B(aNX[u][0], an, b0); MFMA_B(aNX[u][1], an, b1); }
                    else     { MFMA_B(aNH[u][0], an, b0); MFMA_B(aNH[u][1], an, b1); }
                }
            }
        }
    };

    // ---- schedule: all DMA staging up front, ONE barrier ----
    stage_tin(xT + (size_t)(b * T_ + t) * PIMG_HW, t0s);
    if (t > 0) {
        stage_tin(hTrd + (size_t)(b * 2 + 0) * PIMG_HW, t1s);
        stage_tin(hTrd + (size_t)(b * 2 + 1) * PIMG_HW, t2s);
    }
    regA(0);
    __syncthreads();

    const us* A1p = (t > 0) ? A2 + (size_t)(1 * 4 + hg) * ASLAB_HW + lane * 8 : nullptr;
    const us* A2p = (t > 0) ? A2 + (size_t)(2 * 4 + hg) * ASLAB_HW + lane * 8 : nullptr;

    compute(t0s, true, A1p);
    if (t > 0) {
        compute(t1s, false, A2p);
        compute(t2s, false, nullptr);
    }

    // ---- epilogue ----
    float* outp = out + ((size_t)(b * T_ + t)) * HID * HW;
    const int c0   = hg * 16 + kl * 4;
    const int slot = c0 & 31;
    const us* hbuf = (hg < 2) ? t1s : t2s;
    #pragma unroll
    for (int u = 0; u < 2; ++u) {
        #pragma unroll
        for (int g = 0; g < 2; ++g) {
            int orow = 2 * u + g;                 // 0..3
            int gy = gy0 + orow, gx = gx0 + px;
            float hvf[4] = {0.f, 0.f, 0.f, 0.f};
            if (t > 0) {
                const us* hp = hbuf + (size_t)((orow + 1) * 18 + (px + 1)) * CSL + slot;
                #pragma unroll
                for (int q = 0; q < 4; ++q) hvf[q] = bf2f(hp[q]);
            }
            us hv[4];
            #pragma unroll
            for (int q = 0; q < 4; ++q) {
                float sr = __builtin_amdgcn_rcpf(1.f + __expf(-aR[u][g][q]));
                float sz = __builtin_amdgcn_rcpf(1.f + __expf(-aZ[u][g][q]));
                float ag = aNX[u][g][q] + sr * aNH[u][g][q];
                float nn = 2.f * __builtin_amdgcn_rcpf(1.f + __expf(-2.f * ag)) - 1.f;
                float hn = nn + sz * (hvf[q] - nn);
                outp[(size_t)(c0 + q) * HW + gy * WW + gx] = hn;
                hv[q] = f2bf(hn);
            }
            us* hd = hTwr + (size_t)(b * 2 + (c0 >> 5)) * PIMG_HW
                   + (size_t)((gy + 1) * 66 + (gx + 1)) * CSL + slot;
            *(uint2*)hd = *(const uint2*)hv;
        }
    }
}

// ================= round-4 fallback (tiny ws) =================
constexpr int F_AROWB = 640;
constexpr int R4_ASLAB = 48 * 9 * KCH;
constexpr int R4_AVEC  = R4_ASLAB / 8;
constexpr int R4_ATOT  = 12 * R4_ASLAB;
constexpr int FPR = 10, FPC = 18;
__global__ void wconv_r4(const float* __restrict__ Wi, const float* __restrict__ Wh,
                         us* __restrict__ A2) {
    int idx = blockIdx.x * 256 + threadIdx.x;
    if (idx >= R4_ATOT) return;
    int ic = idx & 31; int r1 = idx >> 5;
    int tap = r1 % 9; int r2 = r1 / 9;
    int m = r2 & 15; int r3 = r2 >> 4;
    int gt = r3 % 3; int r4 = r3 / 3;
    int hg = r4 & 3; int ch = r4 >> 2;
    int o = gt * 64 + hg * 16 + m;
    float w = (ch == 0) ? Wi[(o * CIN + ic) * 9 + tap]
                        : Wh[(o * HID + (ch - 1) * 32 + ic) * 9 + tap];
    A2[idx] = f2bf(w);
}
__global__ __launch_bounds__(256, 2) void convgru_r4(
    const float* __restrict__ x, const us* __restrict__ A2,
    const float* hall, float* out, int t)
{
    __shared__ __align__(16) us tin[FPR * FPC * 40];
    __shared__ __align__(16) us Alr[48 * (F_AROWB / 2)];
    const int tid = threadIdx.x;
    const int lane = tid & 63, wave = tid >> 6;
    const int px = lane & 15, kl = lane >> 4;
    const int ty = blockIdx.x >> 2, tx = blockIdx.x & 3;
    const int hg = blockIdx.y, b = blockIdx.z;
    const int gy0 = ty * 8, gx0 = tx * 16;
    const int nch = (t > 0) ? 3 : 1;
    const float* hb = (t > 0) ? (hall + ((size_t)(b * T_ + t - 1)) * HID * HW) : nullptr;
    const float* xb = x + ((size_t)(b * T_ + t)) * CIN * HW;
    f32x4 accR[2] = {}, accZ[2] = {}, accNX[2] = {}, accNH[2] = {};
    float ireg[23]; bf16x8 areg[7];
    auto load_in = [&](int ch) {
        const float* src = (ch == 0) ? xb : (hb + (size_t)(ch - 1) * 32 * HW);
        #pragma unroll
        for (int j = 0; j < 23; ++j) {
            int e = tid + j * 256; float v = 0.f;
            if (e < FPR * FPC * 32) {
                int ic = e / (FPR * FPC); int rem = e - ic * (FPR * FPC);
                int r = rem / FPC, c = rem - r * FPC;
                int gy = gy0 + r - 1, gx = gx0 + c - 1;
                if ((unsigned)gy < (unsigned)HH && (unsigned)gx < (unsigned)WW)
                    v = src[ic * HW + gy * WW + gx];
            }
            ireg[j] = v;
        }
    };
    auto load_Ar = [&](int ch) {
        const us* s = A2 + (size_t)(ch * 4 + hg) * R4_ASLAB;
        #pragma unroll
        for (int j = 0; j < 7; ++j) { int v = tid + j * 256; if (v < R4_AVEC) areg[j] = *(const bf16x8*)(s + v * 8); }
    };
    auto write_in = [&]() {
        #pragma unroll
        for (int j = 0; j < 23; ++j) {
            int e = tid + j * 256;
            if (e < FPR * FPC * 32) {
                int ic = e / (FPR * FPC); int rem = e - ic * (FPR * FPC);
                int r = rem / FPC, c = rem - r * FPC;
                tin[(r * FPC + c) * 40 + ic] = f2bf(ireg[j]);
            }
        }
    };
    auto write_Ar = [&]() {
        #pragma unroll
        for (int j = 0; j < 7; ++j) {
            int v = tid + j * 256;
            if (v < R4_AVEC) {
                int row = v / 36; int kb = (v - row * 36) * 16;
                char* dst = (char*)Alr + row * F_AROWB + (kb ^ ((row & 7) << 4));
                *(bf16x8*)dst = areg[j];
            }
        }
    };
    const int rb0 = ((wave * 2 + 0) * FPC + px) * 40 + kl * 8;
    const int rb1 = rb0 + FPC * 40;
    const int swA = (px & 7) << 4;
    auto compute = [&](bool isX) {
        #pragma unroll
        for (int tap = 0; tap < 9; ++tap) {
            const int dy = tap / 3, dx = tap - 3 * dy;
            const int toff = (dy * FPC + dx) * 40;
            bf16x8 b0 = *(const bf16x8*)(tin + rb0 + toff);
            bf16x8 b1 = *(const bf16x8*)(tin + rb1 + toff);
            const char* ab = (const char*)Alr + px * F_AROWB + ((tap * 64 + kl * 16) ^ swA);
            bf16x8 ar = *(const bf16x8*)(ab);
            bf16x8 az = *(const bf16x8*)(ab + 16 * F_AROWB);
            bf16x8 an = *(const bf16x8*)(ab + 32 * F_AROWB);
            MFMA_B(accR[0], ar, b0); MFMA_B(accR[1], ar, b1);
            MFMA_B(accZ[0], az, b0); MFMA_B(accZ[1], az, b1);
            if (isX) { MFMA_B(accNX[0], an, b0); MFMA_B(accNX[1], an, b1); }
            else     { MFMA_B(accNH[0], an, b0); MFMA_B(accNH[1], an, b1); }
        }
    };
    load_in(0); load_Ar(0); write_in(); write_Ar();
    __syncthreads();
    for (int ch = 0; ch < nch; ++ch) {
        if (ch + 1 < nch) { load_in(ch + 1); load_Ar(ch + 1); }
        compute(ch == 0);
        __syncthreads();
        if (ch + 1 < nch) { write_in(); write_Ar(); __syncthreads(); }
    }
    float* outp = out + ((size_t)(b * T_ + t)) * HID * HW;
    #pragma unroll
    for (int g = 0; g < 2; ++g) {
        int gy = gy0 + wave * 2 + g; int gx = gx0 + px;
        #pragma unroll
        for (int q = 0; q < 4; ++q) {
            int c = hg * 16 + kl * 4 + q;
            float sr = 1.f / (1.f + expf(-accR[g][q]));
            float sz = 1.f / (1.f + expf(-accZ[g][q]));
            float nn = tanhf(accNX[g][q] + sr * accNH[g][q]);
            float hv = hb ? hb[(size_t)c * HW + gy * WW + gx] : 0.f;
            outp[(size_t)c * HW + gy * WW + gx] = (1.f - sz) * nn + sz * hv;
        }
    }
}

extern "C" void kernel_launch(void* const* d_in, const int* in_sizes, int n_in,
                              void* d_out, int out_size, void* d_ws, size_t ws_size,
                              hipStream_t stream) {
    const float* x  = (const float*)d_in[0];
    const float* Wi = (const float*)d_in[1];
    const float* Wh = (const float*)d_in[2];
    float* out = (float*)d_out;

    if (ws_size >= WS_NEED_BYTES) {
        us* A2  = (us*)d_ws;
        us* xT  = A2 + XT_OFF;
        us* hT0 = A2 + HT_OFF;
        us* hT1 = hT0 + HTBUF_HW;

        prep<<<PB_TOTAL, 256, 0, stream>>>(x, Wi, Wh, A2, xT, hT0);
        for (int t = 0; t < T_; ++t) {
            us* rd = (t & 1) ? hT1 : hT0;
            us* wr = (t & 1) ? hT0 : hT1;
            convgru_step<<<dim3(64, 1, 4), 256, 0, stream>>>(xT, A2, rd, wr, out, t);
        }
    } else {
        us* A2 = (us*)d_ws;
        wconv_r4<<<(R4_ATOT + 255) / 256, 256, 0, stream>>>(Wi, Wh, A2);
        for (int t = 0; t < T_; ++t)
            convgru_r4<<<dim3(32, 4, 4), 256, 0, stream>>>(x, A2, out, out, t);
    }
}